// Round 1
// baseline (1553.349 us; speedup 1.0000x reference)
//
#include <hip/hip_runtime.h>

// MeshAttention on gfx950 — round 1: correct fp32 fused implementation.
// B=4, H=8, E=1500, D=256, DK=DV=32, PMAX+1=6, mask = dist<=3.
// Outputs (concat in d_out): x_out [B,D,E] (1536000), attn [B,H,E,E] (72000000),
// attn_per_edge [B,E] (6000).

#define E_ 1500
#define D_ 256
#define HH 8
#define BB 4
#define MM (BB * E_)        // 6000 rows
#define QT 32               // q-tile
#define KT 128              // key-tile
#define NKT 12              // ceil(1500/128)
#define NQT 47              // ceil(1500/32)

// ---------------------------------------------------------------- transpose
__global__ __launch_bounds__(256) void t0_transpose(const float* __restrict__ x,
                                                    float* __restrict__ xt) {
  __shared__ float tl[32][33];
  const int b = blockIdx.z;
  const int dt = blockIdx.x * 32;
  const int et = blockIdx.y * 32;
  const int tx = threadIdx.x, ty = threadIdx.y;  // 32 x 8
#pragma unroll
  for (int j = 0; j < 4; j++) {
    int d = dt + ty + j * 8;
    int e = et + tx;
    float v = 0.f;
    if (e < E_) v = x[(size_t)b * D_ * E_ + (size_t)d * E_ + e];
    tl[ty + j * 8][tx] = v;
  }
  __syncthreads();
#pragma unroll
  for (int j = 0; j < 4; j++) {
    int e = et + ty + j * 8;
    int d = dt + tx;
    if (e < E_) xt[((size_t)b * E_ + e) * D_ + d] = tl[tx][ty + j * 8];
  }
}

// ---------------------------------------------------------------- layernorm
__global__ __launch_bounds__(256) void k1_ln(const float* __restrict__ xt,
                                             const float* __restrict__ lnw,
                                             const float* __restrict__ lnb,
                                             float* __restrict__ qn) {
  const int m = blockIdx.x;
  const int t = threadIdx.x;
  float v = xt[(size_t)m * D_ + t];
  float s = v, s2 = v * v;
#pragma unroll
  for (int o = 1; o < 64; o <<= 1) {
    s += __shfl_xor(s, o);
    s2 += __shfl_xor(s2, o);
  }
  __shared__ float ps[4], ps2[4], mv[2];
  const int w = t >> 6;
  if ((t & 63) == 0) { ps[w] = s; ps2[w] = s2; }
  __syncthreads();
  if (t == 0) {
    float ts = ps[0] + ps[1] + ps[2] + ps[3];
    float ts2 = ps2[0] + ps2[1] + ps2[2] + ps2[3];
    float mu = ts * (1.f / 256.f);
    float var = ts2 * (1.f / 256.f) - mu * mu;
    mv[0] = mu;
    mv[1] = rsqrtf(var + 1e-6f);
  }
  __syncthreads();
  qn[(size_t)m * D_ + t] = (v - mv[0]) * mv[1] * lnw[t] + lnb[t];
}

// ------------------------------------------------- projections (3 GEMMs)
// grid.y: 0 -> q = LN(x)@Wq * 1/sqrt(32); 1 -> k = s@Wk; 2 -> v = s@Wv
__global__ __launch_bounds__(256) void k_gemm_proj(
    const float* __restrict__ xt, const float* __restrict__ qn,
    const float* __restrict__ Wq, const float* __restrict__ Wk,
    const float* __restrict__ Wv, float* __restrict__ qb,
    float* __restrict__ kb, float* __restrict__ vb) {
  __shared__ __align__(16) float AT[32 * 36];   // [k][row]
  __shared__ __align__(16) float Bt[32 * 260];  // [k][n]
  const int which = blockIdx.y;
  const float* src = (which == 0) ? qn : xt;
  const float* W = (which == 0) ? Wq : ((which == 1) ? Wk : Wv);
  float* dst = (which == 0) ? qb : ((which == 1) ? kb : vb);
  const float scale = (which == 0) ? 0.17677669529663687f : 1.0f;
  const int m0 = blockIdx.x * 32;
  const int t = threadIdx.x;
  const int rg = t >> 5, cg = t & 31;
  float acc[4][8];
#pragma unroll
  for (int i = 0; i < 4; i++)
#pragma unroll
    for (int c = 0; c < 8; c++) acc[i][c] = 0.f;

  for (int k0 = 0; k0 < 256; k0 += 32) {
    __syncthreads();
    {  // stage A transposed
      int r = t >> 3, cq = t & 7;
      int m = m0 + r;
      if (m > MM - 1) m = MM - 1;
      float4 f = *(const float4*)(src + (size_t)m * 256 + k0 + cq * 4);
      AT[(cq * 4 + 0) * 36 + r] = f.x;
      AT[(cq * 4 + 1) * 36 + r] = f.y;
      AT[(cq * 4 + 2) * 36 + r] = f.z;
      AT[(cq * 4 + 3) * 36 + r] = f.w;
    }
#pragma unroll
    for (int ii = 0; ii < 8; ii++) {  // stage B
      int id = t + 256 * ii;
      int kk = id >> 6, nq = id & 63;
      *(float4*)(Bt + kk * 260 + nq * 4) =
          *(const float4*)(W + (size_t)(k0 + kk) * 256 + nq * 4);
    }
    __syncthreads();
#pragma unroll
    for (int kk = 0; kk < 32; kk++) {
      float4 a4 = *(float4*)(AT + kk * 36 + rg * 4);
      float4 b0 = *(float4*)(Bt + kk * 260 + cg * 8);
      float4 b1 = *(float4*)(Bt + kk * 260 + cg * 8 + 4);
      float aa[4] = {a4.x, a4.y, a4.z, a4.w};
      float bb[8] = {b0.x, b0.y, b0.z, b0.w, b1.x, b1.y, b1.z, b1.w};
#pragma unroll
      for (int i = 0; i < 4; i++)
#pragma unroll
        for (int c = 0; c < 8; c++) acc[i][c] = fmaf(aa[i], bb[c], acc[i][c]);
    }
  }
#pragma unroll
  for (int i = 0; i < 4; i++) {
    int m = m0 + rg * 4 + i;
    if (m < MM) {
      float4 o0 = make_float4(acc[i][0] * scale, acc[i][1] * scale,
                              acc[i][2] * scale, acc[i][3] * scale);
      float4 o1 = make_float4(acc[i][4] * scale, acc[i][5] * scale,
                              acc[i][6] * scale, acc[i][7] * scale);
      *(float4*)(dst + (size_t)m * 256 + cg * 8) = o0;
      *(float4*)(dst + (size_t)m * 256 + cg * 8 + 4) = o1;
    }
  }
}

// ---------------------------------------------------------------- attention
// block = (qtile, h, b); 256 threads; two passes over key tiles (recompute QK)
__global__ __launch_bounds__(256) void k2_attn(
    const float* __restrict__ qb, const float* __restrict__ kb,
    const float* __restrict__ vb, const int* __restrict__ dist,
    const float* __restrict__ rpr, float* __restrict__ attn,
    float* __restrict__ ao, float* __restrict__ asum) {
  __shared__ __align__(16) float qT[32 * 36];    // [d][q]
  __shared__ __align__(16) float kT[32 * 132];   // [d][k]
  __shared__ __align__(16) float vT[32 * 132];   // [dv][k]
  __shared__ __align__(16) float lt[32 * 132];   // [q][k] logits / probs
  __shared__ float qdr[32 * 8];                  // [q][p]
  __shared__ float rowm[32], rowl[32];

  const int qt = blockIdx.x, h = blockIdx.y, b = blockIdx.z;
  const int q0 = qt * QT;
  const int t = threadIdx.x;
  const int bh = b * HH + h;

  {  // stage q tile (transposed), q pre-scaled by 1/sqrt(32)
    int r = t >> 3, cq = t & 7;
    int q = q0 + r;
    if (q > E_ - 1) q = E_ - 1;
    float4 f = *(const float4*)(qb + ((size_t)b * E_ + q) * 256 + h * 32 + cq * 4);
    qT[(cq * 4 + 0) * 36 + r] = f.x;
    qT[(cq * 4 + 1) * 36 + r] = f.y;
    qT[(cq * 4 + 2) * 36 + r] = f.z;
    qT[(cq * 4 + 3) * 36 + r] = f.w;
  }
  if (t < 32) { rowm[t] = -1e30f; rowl[t] = 0.f; }
  __syncthreads();
  if (t < 192) {  // q . base_rpr  -> [32 q][6 p]
    int q = t / 6, p = t % 6;
    float s = 0.f;
#pragma unroll
    for (int d = 0; d < 32; d++) s += qT[d * 36 + q] * rpr[p * 32 + d];
    qdr[q * 8 + p] = s;
  }

  const int qgA = t >> 5, kgA = t & 31;  // QK mapping: 8x32 -> 4q x 4k tiles

  // ----- pass 1: online max & sum(exp) per row
  for (int kt = 0; kt < NKT; kt++) {
    const int k0 = kt * KT;
    __syncthreads();
#pragma unroll
    for (int ii = 0; ii < 4; ii++) {  // stage K transposed
      int id = t + 256 * ii;
      int kk = id >> 3, cq = id & 7;
      int k = k0 + kk;
      float4 f = make_float4(0.f, 0.f, 0.f, 0.f);
      if (k < E_)
        f = *(const float4*)(kb + ((size_t)b * E_ + k) * 256 + h * 32 + cq * 4);
      kT[(cq * 4 + 0) * 132 + kk] = f.x;
      kT[(cq * 4 + 1) * 132 + kk] = f.y;
      kT[(cq * 4 + 2) * 132 + kk] = f.z;
      kT[(cq * 4 + 3) * 132 + kk] = f.w;
    }
    __syncthreads();
    float a[4][4];
#pragma unroll
    for (int i = 0; i < 4; i++)
#pragma unroll
      for (int j = 0; j < 4; j++) a[i][j] = 0.f;
#pragma unroll
    for (int d = 0; d < 32; d++) {
      float4 q4 = *(float4*)(qT + d * 36 + qgA * 4);
      float4 k4 = *(float4*)(kT + d * 132 + kgA * 4);
      float qa[4] = {q4.x, q4.y, q4.z, q4.w};
      float ka[4] = {k4.x, k4.y, k4.z, k4.w};
#pragma unroll
      for (int i = 0; i < 4; i++)
#pragma unroll
        for (int j = 0; j < 4; j++) a[i][j] = fmaf(qa[i], ka[j], a[i][j]);
    }
#pragma unroll
    for (int i = 0; i < 4; i++) {  // bias + mask -> lt
      int q = q0 + qgA * 4 + i;
      int qc = (q < E_) ? q : (E_ - 1);
      const int* drow = dist + ((size_t)b * E_ + qc) * E_;
      float ov[4];
#pragma unroll
      for (int j = 0; j < 4; j++) {
        int k = k0 + kgA * 4 + j;
        float val = -1e9f;
        if (k < E_) {
          int dd = drow[k];
          if (dd <= 3) val = a[i][j] + qdr[(qgA * 4 + i) * 8 + dd];
        }
        ov[j] = val;
      }
      *(float4*)(lt + (qgA * 4 + i) * 132 + kgA * 4) =
          make_float4(ov[0], ov[1], ov[2], ov[3]);
    }
    __syncthreads();
    {  // per-row online m/l update (8 lanes per row, within-wave shuffles)
      int q = t >> 3, l8 = t & 7;
      float4 c0 = *(float4*)(lt + q * 132 + (l8 + 0) * 4);
      float4 c1 = *(float4*)(lt + q * 132 + (l8 + 8) * 4);
      float4 c2 = *(float4*)(lt + q * 132 + (l8 + 16) * 4);
      float4 c3 = *(float4*)(lt + q * 132 + (l8 + 24) * 4);
      float va[16] = {c0.x, c0.y, c0.z, c0.w, c1.x, c1.y, c1.z, c1.w,
                      c2.x, c2.y, c2.z, c2.w, c3.x, c3.y, c3.z, c3.w};
      float tm = va[0];
#pragma unroll
      for (int u = 1; u < 16; u++) tm = fmaxf(tm, va[u]);
      tm = fmaxf(tm, __shfl_xor(tm, 1));
      tm = fmaxf(tm, __shfl_xor(tm, 2));
      tm = fmaxf(tm, __shfl_xor(tm, 4));
      float mo = rowm[q];
      float mn = fmaxf(mo, tm);
      float ts = 0.f;
#pragma unroll
      for (int u = 0; u < 16; u++) ts += __expf(va[u] - mn);
      ts += __shfl_xor(ts, 1);
      ts += __shfl_xor(ts, 2);
      ts += __shfl_xor(ts, 4);
      if (l8 == 0) {
        rowm[q] = mn;
        rowl[q] = rowl[q] * __expf(mo - mn) + ts;
      }
    }
  }
  __syncthreads();

  // ----- pass 2: recompute -> write attn, accumulate per-key sums, PV
  float pv[4][4];
#pragma unroll
  for (int i = 0; i < 4; i++)
#pragma unroll
    for (int c = 0; c < 4; c++) pv[i][c] = 0.f;
  const int qgP = t >> 5, vg = (t >> 2) & 7, ks = t & 3;

  for (int kt = 0; kt < NKT; kt++) {
    const int k0 = kt * KT;
    __syncthreads();
#pragma unroll
    for (int ii = 0; ii < 4; ii++) {  // stage K and V transposed
      int id = t + 256 * ii;
      int kk = id >> 3, cq = id & 7;
      int k = k0 + kk;
      float4 f = make_float4(0.f, 0.f, 0.f, 0.f);
      float4 g = make_float4(0.f, 0.f, 0.f, 0.f);
      if (k < E_) {
        f = *(const float4*)(kb + ((size_t)b * E_ + k) * 256 + h * 32 + cq * 4);
        g = *(const float4*)(vb + ((size_t)b * E_ + k) * 256 + h * 32 + cq * 4);
      }
      kT[(cq * 4 + 0) * 132 + kk] = f.x;
      kT[(cq * 4 + 1) * 132 + kk] = f.y;
      kT[(cq * 4 + 2) * 132 + kk] = f.z;
      kT[(cq * 4 + 3) * 132 + kk] = f.w;
      vT[(cq * 4 + 0) * 132 + kk] = g.x;
      vT[(cq * 4 + 1) * 132 + kk] = g.y;
      vT[(cq * 4 + 2) * 132 + kk] = g.z;
      vT[(cq * 4 + 3) * 132 + kk] = g.w;
    }
    __syncthreads();
    float a[4][4];
#pragma unroll
    for (int i = 0; i < 4; i++)
#pragma unroll
      for (int j = 0; j < 4; j++) a[i][j] = 0.f;
#pragma unroll
    for (int d = 0; d < 32; d++) {
      float4 q4 = *(float4*)(qT + d * 36 + qgA * 4);
      float4 k4 = *(float4*)(kT + d * 132 + kgA * 4);
      float qa[4] = {q4.x, q4.y, q4.z, q4.w};
      float ka[4] = {k4.x, k4.y, k4.z, k4.w};
#pragma unroll
      for (int i = 0; i < 4; i++)
#pragma unroll
        for (int j = 0; j < 4; j++) a[i][j] = fmaf(qa[i], ka[j], a[i][j]);
    }
#pragma unroll
    for (int i = 0; i < 4; i++) {
      int q = q0 + qgA * 4 + i;
      bool qok = (q < E_);
      int qc = qok ? q : (E_ - 1);
      const int* drow = dist + ((size_t)b * E_ + qc) * E_;
      float mf = rowm[qgA * 4 + i];
      float il = 1.f / rowl[qgA * 4 + i];
      float ov[4];
#pragma unroll
      for (int j = 0; j < 4; j++) {
        int k = k0 + kgA * 4 + j;
        float p = 0.f;
        if (qok && k < E_) {
          int dd = drow[k];
          if (dd <= 3)
            p = __expf(a[i][j] + qdr[(qgA * 4 + i) * 8 + dd] - mf) * il;
        }
        ov[j] = p;
      }
      *(float4*)(lt + (qgA * 4 + i) * 132 + kgA * 4) =
          make_float4(ov[0], ov[1], ov[2], ov[3]);
      if (qok && (k0 + kgA * 4) < E_) {  // E_%4==0 so whole quad in-range
        float* arow = attn + ((size_t)bh * E_ + q) * E_ + k0 + kgA * 4;
        *(float2*)(arow) = make_float2(ov[0], ov[1]);
        *(float2*)(arow + 2) = make_float2(ov[2], ov[3]);
      }
    }
    __syncthreads();
    if (t < 128) {  // per-key column sums (heads+q accumulate via atomics)
      int k = k0 + t;
      if (k < E_) {
        float s = 0.f;
#pragma unroll
        for (int q = 0; q < 32; q++) s += lt[q * 132 + t];
        atomicAdd(asum + b * E_ + k, s);
      }
    }
#pragma unroll
    for (int jq = 0; jq < 8; jq++) {  // PV: 4q x 4dv, k split over 4 lanes
      int kq = ks + jq * 4;
      float4 p4[4], v4[4];
#pragma unroll
      for (int i = 0; i < 4; i++)
        p4[i] = *(float4*)(lt + (qgP * 4 + i) * 132 + kq * 4);
#pragma unroll
      for (int c = 0; c < 4; c++)
        v4[c] = *(float4*)(vT + (vg * 4 + c) * 132 + kq * 4);
#pragma unroll
      for (int i = 0; i < 4; i++)
#pragma unroll
        for (int c = 0; c < 4; c++)
          pv[i][c] += p4[i].x * v4[c].x + p4[i].y * v4[c].y +
                      p4[i].z * v4[c].z + p4[i].w * v4[c].w;
    }
  }
#pragma unroll
  for (int i = 0; i < 4; i++)
#pragma unroll
    for (int c = 0; c < 4; c++) {
      float v = pv[i][c];
      v += __shfl_xor(v, 1);
      v += __shfl_xor(v, 2);
      pv[i][c] = v;
    }
  if (ks == 0) {
#pragma unroll
    for (int i = 0; i < 4; i++) {
      int q = q0 + qgP * 4 + i;
      if (q < E_)
        *(float4*)(ao + ((size_t)b * E_ + q) * 256 + h * 32 + vg * 4) =
            make_float4(pv[i][0], pv[i][1], pv[i][2], pv[i][3]);
    }
  }
}

// ------------------------------------------- FC + residual + transpose out
__global__ __launch_bounds__(256) void k3_fc(const float* __restrict__ ao,
                                             const float* __restrict__ Wfc,
                                             const float* __restrict__ xt,
                                             float* __restrict__ xout) {
  __shared__ __align__(16) float smem[9472];  // AT(1152) + Bt(8320) | ot(9472)
  float* AT = smem;
  float* Bt = smem + 1152;
  float* ot = smem;  // reused after compute
  const int m0 = blockIdx.x * 32;
  const int t = threadIdx.x;
  const int rg = t >> 5, cg = t & 31;
  float acc[4][8];
#pragma unroll
  for (int i = 0; i < 4; i++)
#pragma unroll
    for (int c = 0; c < 8; c++) acc[i][c] = 0.f;

  for (int k0 = 0; k0 < 256; k0 += 32) {
    __syncthreads();
    {
      int r = t >> 3, cq = t & 7;
      int m = m0 + r;
      if (m > MM - 1) m = MM - 1;
      float4 f = *(const float4*)(ao + (size_t)m * 256 + k0 + cq * 4);
      AT[(cq * 4 + 0) * 36 + r] = f.x;
      AT[(cq * 4 + 1) * 36 + r] = f.y;
      AT[(cq * 4 + 2) * 36 + r] = f.z;
      AT[(cq * 4 + 3) * 36 + r] = f.w;
    }
#pragma unroll
    for (int ii = 0; ii < 8; ii++) {
      int id = t + 256 * ii;
      int kk = id >> 6, nq = id & 63;
      *(float4*)(Bt + kk * 260 + nq * 4) =
          *(const float4*)(Wfc + (size_t)(k0 + kk) * 256 + nq * 4);
    }
    __syncthreads();
#pragma unroll
    for (int kk = 0; kk < 32; kk++) {
      float4 a4 = *(float4*)(AT + kk * 36 + rg * 4);
      float4 b0 = *(float4*)(Bt + kk * 260 + cg * 8);
      float4 b1 = *(float4*)(Bt + kk * 260 + cg * 8 + 4);
      float aa[4] = {a4.x, a4.y, a4.z, a4.w};
      float bb[8] = {b0.x, b0.y, b0.z, b0.w, b1.x, b1.y, b1.z, b1.w};
#pragma unroll
      for (int i = 0; i < 4; i++)
#pragma unroll
        for (int c = 0; c < 8; c++) acc[i][c] = fmaf(aa[i], bb[c], acc[i][c]);
    }
  }
  __syncthreads();
  // residual + store into transpose tile [d][row] pitch 37
#pragma unroll
  for (int i = 0; i < 4; i++) {
    int m = m0 + rg * 4 + i;
    int mc = (m < MM) ? m : (MM - 1);
    float4 r0 = *(const float4*)(xt + (size_t)mc * 256 + cg * 8);
    float4 r1 = *(const float4*)(xt + (size_t)mc * 256 + cg * 8 + 4);
    float rr[8] = {r0.x, r0.y, r0.z, r0.w, r1.x, r1.y, r1.z, r1.w};
#pragma unroll
    for (int c = 0; c < 8; c++)
      ot[(cg * 8 + c) * 37 + rg * 4 + i] = acc[i][c] + rr[c];
  }
  __syncthreads();
  {
    int l = t & 31, dg = t >> 5;
    int m = m0 + l;
    if (m < MM) {
      int b = m / E_, e = m % E_;
      float* obase = xout + (size_t)b * D_ * E_ + e;
#pragma unroll
      for (int ii = 0; ii < 32; ii++) {
        int d = dg + ii * 8;
        obase[(size_t)d * E_] = ot[d * 37 + l];
      }
    }
  }
}

// ------------------------------------------------- mask column counts
__global__ __launch_bounds__(128) void k4_valid(const int* __restrict__ dist,
                                                int* __restrict__ valid) {
  const int b = blockIdx.z, qs = blockIdx.y;
  const int k = blockIdx.x * 128 + threadIdx.x;
  if (k >= E_) return;
  int q1 = qs * 188;
  int q2 = q1 + 188;
  if (q2 > E_) q2 = E_;
  int cnt = 0;
  const int* dbase = dist + (size_t)b * E_ * E_ + k;
  for (int q = q1; q < q2; q++) cnt += (dbase[(size_t)q * E_] <= 3) ? 1 : 0;
  atomicAdd(valid + b * E_ + k, cnt);
}

__global__ __launch_bounds__(256) void k5_div(const float* __restrict__ asum,
                                              const int* __restrict__ valid,
                                              float* __restrict__ ape) {
  int i = blockIdx.x * 256 + threadIdx.x;
  if (i < BB * E_) ape[i] = asum[i] / (float)valid[i];
}

// ---------------------------------------------------------------- launcher
extern "C" void kernel_launch(void* const* d_in, const int* in_sizes, int n_in,
                              void* d_out, int out_size, void* d_ws,
                              size_t ws_size, hipStream_t stream) {
  const float* x = (const float*)d_in[0];      // [4,256,1500]
  const int* dist = (const int*)d_in[1];       // [4,1500,1500]
  const float* Wq = (const float*)d_in[2];
  const float* Wk = (const float*)d_in[3];
  const float* Wv = (const float*)d_in[4];
  const float* Wfc = (const float*)d_in[5];
  const float* lnw = (const float*)d_in[6];
  const float* lnb = (const float*)d_in[7];
  const float* rpr = (const float*)d_in[8];    // [6,32]

  float* out0 = (float*)d_out;                 // x_out [4,256,1500]
  float* attn = out0 + 1536000;                // [4,8,1500,1500]
  float* ape = out0 + 73536000;                // [4,1500]

  float* ws = (float*)d_ws;
  float* xt = ws;                  // s = x^T  [6000,256]
  float* qn = ws + 1536000;        // LN(s)    [6000,256]
  float* qbuf = ws + 3072000;      // scaled q [6000,256]
  float* kbuf = ws + 4608000;
  float* vbuf = ws + 6144000;
  float* ao = ws + 7680000;        // attn @ v [6000,256]
  float* asum = ws + 9216000;      // [6000]
  int* valid = (int*)(ws + 9222000);  // [6000]

  hipMemsetAsync(asum, 0, 6000 * sizeof(float), stream);
  hipMemsetAsync(valid, 0, 6000 * sizeof(int), stream);

  t0_transpose<<<dim3(8, 47, 4), dim3(32, 8), 0, stream>>>(x, xt);
  k1_ln<<<MM, 256, 0, stream>>>(xt, lnw, lnb, qn);
  k_gemm_proj<<<dim3(188, 3), 256, 0, stream>>>(xt, qn, Wq, Wk, Wv, qbuf, kbuf,
                                                vbuf);
  k2_attn<<<dim3(NQT, HH, BB), 256, 0, stream>>>(qbuf, kbuf, vbuf, dist, rpr,
                                                 attn, ao, asum);
  k3_fc<<<188, 256, 0, stream>>>(ao, Wfc, xt, out0);
  k4_valid<<<dim3(12, 8, 4), 128, 0, stream>>>(dist, valid);
  k5_div<<<24, 256, 0, stream>>>(asum, valid, ape);
}

// Round 2
// 797.814 us; speedup vs baseline: 1.9470x; 1.9470x over previous
//
#include <hip/hip_runtime.h>

// MeshAttention on gfx950 — round 2: MFMA bf16 attention, max-free softmax,
// single PV pass + normalize-on-recompute pass, fused valid-count, XCD swizzle.
// B=4, H=8, E=1500, D=256, DK=DV=32, P+1=6, mask = dist<=3.

#define E_ 1500
#define D_ 256
#define HH 8
#define BB 4
#define MM (BB * E_)  // 6000
#define NKT 12        // ceil(1500/128)

typedef float f32x4 __attribute__((ext_vector_type(4)));
typedef short short8 __attribute__((ext_vector_type(8)));

static __device__ inline unsigned short f2bf(float f) {
  unsigned u = __float_as_uint(f);
  unsigned r = (u + 0x7fff + ((u >> 16) & 1)) >> 16;
  return (unsigned short)r;
}
static __device__ inline float bf2f(unsigned short u) {
  return __uint_as_float(((unsigned)u) << 16);
}

// ---------------------------------------------------------------- transpose
__global__ __launch_bounds__(256) void t0_transpose(const float* __restrict__ x,
                                                    float* __restrict__ xt) {
  __shared__ float tl[32][33];
  const int b = blockIdx.z;
  const int dt = blockIdx.x * 32;
  const int et = blockIdx.y * 32;
  const int tx = threadIdx.x, ty = threadIdx.y;  // 32 x 8
#pragma unroll
  for (int j = 0; j < 4; j++) {
    int d = dt + ty + j * 8;
    int e = et + tx;
    float v = 0.f;
    if (e < E_) v = x[(size_t)b * D_ * E_ + (size_t)d * E_ + e];
    tl[ty + j * 8][tx] = v;
  }
  __syncthreads();
#pragma unroll
  for (int j = 0; j < 4; j++) {
    int e = et + ty + j * 8;
    int d = dt + tx;
    if (e < E_) xt[((size_t)b * E_ + e) * D_ + d] = tl[tx][ty + j * 8];
  }
}

// ---------------------------------------------------------------- layernorm
__global__ __launch_bounds__(256) void k1_ln(const float* __restrict__ xt,
                                             const float* __restrict__ lnw,
                                             const float* __restrict__ lnb,
                                             float* __restrict__ qn) {
  const int m = blockIdx.x;
  const int t = threadIdx.x;
  float v = xt[(size_t)m * D_ + t];
  float s = v, s2 = v * v;
#pragma unroll
  for (int o = 1; o < 64; o <<= 1) {
    s += __shfl_xor(s, o);
    s2 += __shfl_xor(s2, o);
  }
  __shared__ float ps[4], ps2[4], mv[2];
  const int w = t >> 6;
  if ((t & 63) == 0) { ps[w] = s; ps2[w] = s2; }
  __syncthreads();
  if (t == 0) {
    float ts = ps[0] + ps[1] + ps[2] + ps[3];
    float ts2 = ps2[0] + ps2[1] + ps2[2] + ps2[3];
    float mu = ts * (1.f / 256.f);
    float var = ts2 * (1.f / 256.f) - mu * mu;
    mv[0] = mu;
    mv[1] = rsqrtf(var + 1e-6f);
  }
  __syncthreads();
  qn[(size_t)m * D_ + t] = (v - mv[0]) * mv[1] * lnw[t] + lnb[t];
}

// ------------------------------------------------- projections -> bf16
// grid.y: 0 -> q = LN(x)@Wq * 1/sqrt(32); 1 -> k = s@Wk; 2 -> v = s@Wv
__global__ __launch_bounds__(256) void k_gemm_proj(
    const float* __restrict__ xt, const float* __restrict__ qn,
    const float* __restrict__ Wq, const float* __restrict__ Wk,
    const float* __restrict__ Wv, unsigned short* __restrict__ qb,
    unsigned short* __restrict__ kb, unsigned short* __restrict__ vb) {
  __shared__ __align__(16) float AT[32 * 36];   // [k][row]
  __shared__ __align__(16) float Bt[32 * 260];  // [k][n]
  const int which = blockIdx.y;
  const float* src = (which == 0) ? qn : xt;
  const float* W = (which == 0) ? Wq : ((which == 1) ? Wk : Wv);
  unsigned short* dst = (which == 0) ? qb : ((which == 1) ? kb : vb);
  const float scale = (which == 0) ? 0.17677669529663687f : 1.0f;
  const int m0 = blockIdx.x * 32;
  const int t = threadIdx.x;
  const int rg = t >> 5, cg = t & 31;
  float acc[4][8];
#pragma unroll
  for (int i = 0; i < 4; i++)
#pragma unroll
    for (int c = 0; c < 8; c++) acc[i][c] = 0.f;

  for (int k0 = 0; k0 < 256; k0 += 32) {
    __syncthreads();
    {
      int r = t >> 3, cq = t & 7;
      int m = m0 + r;
      if (m > MM - 1) m = MM - 1;
      float4 f = *(const float4*)(src + (size_t)m * 256 + k0 + cq * 4);
      AT[(cq * 4 + 0) * 36 + r] = f.x;
      AT[(cq * 4 + 1) * 36 + r] = f.y;
      AT[(cq * 4 + 2) * 36 + r] = f.z;
      AT[(cq * 4 + 3) * 36 + r] = f.w;
    }
#pragma unroll
    for (int ii = 0; ii < 8; ii++) {
      int id = t + 256 * ii;
      int kk = id >> 6, nq = id & 63;
      *(float4*)(Bt + kk * 260 + nq * 4) =
          *(const float4*)(W + (size_t)(k0 + kk) * 256 + nq * 4);
    }
    __syncthreads();
#pragma unroll
    for (int kk = 0; kk < 32; kk++) {
      float4 a4 = *(float4*)(AT + kk * 36 + rg * 4);
      float4 b0 = *(float4*)(Bt + kk * 260 + cg * 8);
      float4 b1 = *(float4*)(Bt + kk * 260 + cg * 8 + 4);
      float aa[4] = {a4.x, a4.y, a4.z, a4.w};
      float bb[8] = {b0.x, b0.y, b0.z, b0.w, b1.x, b1.y, b1.z, b1.w};
#pragma unroll
      for (int i = 0; i < 4; i++)
#pragma unroll
        for (int c = 0; c < 8; c++) acc[i][c] = fmaf(aa[i], bb[c], acc[i][c]);
    }
  }
#pragma unroll
  for (int i = 0; i < 4; i++) {
    int m = m0 + rg * 4 + i;
    if (m < MM) {
      uint4 o;
      o.x = (unsigned)f2bf(acc[i][0] * scale) |
            ((unsigned)f2bf(acc[i][1] * scale) << 16);
      o.y = (unsigned)f2bf(acc[i][2] * scale) |
            ((unsigned)f2bf(acc[i][3] * scale) << 16);
      o.z = (unsigned)f2bf(acc[i][4] * scale) |
            ((unsigned)f2bf(acc[i][5] * scale) << 16);
      o.w = (unsigned)f2bf(acc[i][6] * scale) |
            ((unsigned)f2bf(acc[i][7] * scale) << 16);
      *(uint4*)(dst + (size_t)m * 256 + cg * 8) = o;
    }
  }
}

// ---------------------------------------------------------------- attention
// Max-free softmax. Sweep 1: QK(mfma) -> exp -> rowsum + unnormalized PV(mfma).
// Sweep 2: recompute QK -> normalized p -> attn write + column sums + counts.
// q pitch / k pitch = 40 bf16 (80 B); pS/vT pitch 136 bf16; apS pitch 140 f32.
__global__ __launch_bounds__(256) void k2_attn(
    const unsigned short* __restrict__ qb, const unsigned short* __restrict__ kb,
    const unsigned short* __restrict__ vb, const int* __restrict__ dist,
    const float* __restrict__ rpr, float* __restrict__ attn,
    float* __restrict__ ao, float* __restrict__ asum,
    float* __restrict__ validf) {
  __shared__ __align__(16) unsigned short qS[32 * 40];
  __shared__ __align__(16) unsigned short kS[128 * 40];
  __shared__ __align__(16) float unionBuf[32 * 140];  // apS | pS+vT
  __shared__ float qdr[32 * 8];
  __shared__ float rowl[32], rinv[32];
  __shared__ float colacc[128], colcnt[128];

  unsigned short* pS = (unsigned short*)unionBuf;  // [32 q][136]
  unsigned short* vT = pS + 32 * 136;              // [32 dv][136]
  float* apS = unionBuf;                           // [32 q][140]

  // XCD-aware decode: blocks 8 apart share (b,qt), differ in h.
  const int n = blockIdx.x;
  const int h = (n >> 3) & 7;
  const int slice = (n & 7) + ((n >> 6) << 3);
  if (slice >= 188) return;
  const int b = slice / 47;
  const int qt = slice % 47;
  const int q0 = qt * 32;
  const int t = threadIdx.x;
  const int w = t >> 6, l = t & 63, quad = l >> 4, l15 = l & 15;
  const int qsub = w & 1, khalf = w >> 1;
  const bool h0 = (h == 0);

  // stage q tile (bf16 rows, pitch 40)
  {
    int r = t >> 3, c8 = t & 7;
    int qg = q0 + r;
    unsigned long long v = 0ull;
    if (qg < E_)
      v = *(const unsigned long long*)(qb + ((size_t)(b * E_ + qg)) * 256 +
                                       h * 32 + c8 * 4);
    *(unsigned long long*)(qS + r * 40 + c8 * 4) = v;
  }
  if (t < 32) rowl[t] = 0.f;
  if (t < 128) { colacc[t] = 0.f; colcnt[t] = 0.f; }
  __syncthreads();

  // q . base_rpr  (only p<=3 ever used, compute 6 anyway)
  if (t < 192) {
    int q = t / 6, p = t - (t / 6) * 6;
    float s = 0.f;
#pragma unroll
    for (int d = 0; d < 32; d++) s += bf2f(qS[q * 40 + d]) * rpr[p * 32 + d];
    qdr[q * 8 + p] = s;
  }
  __syncthreads();

  // loop-invariant A fragment (16 q rows for this wave's qsub)
  short8 aq = *(short8*)(qS + (qsub * 16 + l15) * 40 + quad * 8);
  f32x4 accPV = {0.f, 0.f, 0.f, 0.f};

  // ================= sweep 1: rowsum + unnormalized PV =================
  for (int kt = 0; kt < NKT; kt++) {
    const int k0 = kt * 128;
    __syncthreads();
    {  // stage K (pitch 40) and V transposed (vT[dv][key], pitch 136)
      int r = t >> 1, half = t & 1;
      int kg = k0 + r;
      unsigned short* dk = kS + r * 40 + half * 16;
      if (kg < E_) {
        const unsigned short* kp =
            kb + ((size_t)(b * E_ + kg)) * 256 + h * 32 + half * 16;
        const unsigned short* vp =
            vb + ((size_t)(b * E_ + kg)) * 256 + h * 32 + half * 16;
        uint4 a0 = *(const uint4*)kp;
        uint4 a1 = *(const uint4*)(kp + 8);
        *(uint4*)dk = a0;
        *(uint4*)(dk + 8) = a1;
        uint4 b0 = *(const uint4*)vp;
        uint4 b1 = *(const uint4*)(vp + 8);
        unsigned short vv[16];
        *(uint4*)vv = b0;
        *(uint4*)(vv + 8) = b1;
#pragma unroll
        for (int j = 0; j < 16; j++) vT[(half * 16 + j) * 136 + r] = vv[j];
      } else {
        uint4 z = {0u, 0u, 0u, 0u};
        *(uint4*)dk = z;
        *(uint4*)(dk + 8) = z;
#pragma unroll
        for (int j = 0; j < 16; j++) vT[(half * 16 + j) * 136 + r] = 0;
      }
    }
    __syncthreads();

    // QK mfma: 4 key-subtiles per wave
    f32x4 c[4];
#pragma unroll
    for (int j = 0; j < 4; j++) {
      int ksub = khalf * 4 + j;
      short8 bk = *(short8*)(kS + (ksub * 16 + l15) * 40 + quad * 8);
      f32x4 z = {0.f, 0.f, 0.f, 0.f};
      c[j] = __builtin_amdgcn_mfma_f32_16x16x32_bf16(aq, bk, z, 0, 0, 0);
    }

    // bias + mask + exp; rowsum partials; stage p (bf16) for PV
    float rs[4] = {0.f, 0.f, 0.f, 0.f};
#pragma unroll
    for (int j = 0; j < 4; j++) {
      int ksub = khalf * 4 + j;
      int kcol = k0 + ksub * 16 + l15;
      bool kok = kcol < E_;
#pragma unroll
      for (int r = 0; r < 4; r++) {
        int ql = qsub * 16 + quad * 4 + r;
        int qg = q0 + ql;
        int dd = 8;
        if (kok && qg < E_) dd = dist[((size_t)b * E_ + qg) * E_ + kcol];
        float e = 0.f;
        if (dd <= 3) e = __expf(c[j][r] + qdr[ql * 8 + dd]);
        rs[r] += e;
        pS[ql * 136 + ksub * 16 + l15] = f2bf(e);
      }
    }
#pragma unroll
    for (int r = 0; r < 4; r++) {
      float v = rs[r];
      v += __shfl_xor(v, 1);
      v += __shfl_xor(v, 2);
      v += __shfl_xor(v, 4);
      v += __shfl_xor(v, 8);
      if (l15 == 0) atomicAdd(&rowl[qsub * 16 + quad * 4 + r], v);
    }
    __syncthreads();

    // PV mfma: out[16q x 16dv] per wave, K=128 keys in 4 chunks
#pragma unroll
    for (int ch = 0; ch < 4; ch++) {
      short8 ap = *(short8*)(pS + (qsub * 16 + l15) * 136 + ch * 32 + quad * 8);
      short8 bv =
          *(short8*)(vT + (khalf * 16 + l15) * 136 + ch * 32 + quad * 8);
      accPV = __builtin_amdgcn_mfma_f32_16x16x32_bf16(ap, bv, accPV, 0, 0, 0);
    }
  }
  __syncthreads();
  if (t < 32) {
    float lsum = rowl[t];
    rinv[t] = (lsum > 0.f) ? 1.f / lsum : 0.f;
  }
  __syncthreads();

  // write ao = PV / l   (C layout: row=quad*4+r, col=l15)
#pragma unroll
  for (int r = 0; r < 4; r++) {
    int ql = qsub * 16 + quad * 4 + r;
    int qg = q0 + ql;
    if (qg < E_)
      ao[((size_t)(b * E_ + qg)) * 256 + h * 32 + khalf * 16 + l15] =
          accPV[r] * rinv[ql];
  }

  // ================= sweep 2: normalized attn + column sums =================
  for (int kt = 0; kt < NKT; kt++) {
    const int k0 = kt * 128;
    __syncthreads();
    {  // stage K only
      int r = t >> 1, half = t & 1;
      int kg = k0 + r;
      unsigned short* dk = kS + r * 40 + half * 16;
      if (kg < E_) {
        const unsigned short* kp =
            kb + ((size_t)(b * E_ + kg)) * 256 + h * 32 + half * 16;
        uint4 a0 = *(const uint4*)kp;
        uint4 a1 = *(const uint4*)(kp + 8);
        *(uint4*)dk = a0;
        *(uint4*)(dk + 8) = a1;
      } else {
        uint4 z = {0u, 0u, 0u, 0u};
        *(uint4*)dk = z;
        *(uint4*)(dk + 8) = z;
      }
    }
    __syncthreads();

    f32x4 c[4];
#pragma unroll
    for (int j = 0; j < 4; j++) {
      int ksub = khalf * 4 + j;
      short8 bk = *(short8*)(kS + (ksub * 16 + l15) * 40 + quad * 8);
      f32x4 z = {0.f, 0.f, 0.f, 0.f};
      c[j] = __builtin_amdgcn_mfma_f32_16x16x32_bf16(aq, bk, z, 0, 0, 0);
    }

#pragma unroll
    for (int j = 0; j < 4; j++) {
      int ksub = khalf * 4 + j;
      int kcol = k0 + ksub * 16 + l15;
      bool kok = kcol < E_;
      float cp = 0.f, cc = 0.f;
#pragma unroll
      for (int r = 0; r < 4; r++) {
        int ql = qsub * 16 + quad * 4 + r;
        int qg = q0 + ql;
        int dd = 8;
        if (kok && qg < E_) dd = dist[((size_t)b * E_ + qg) * E_ + kcol];
        float p = 0.f;
        if (dd <= 3) {
          p = __expf(c[j][r] + qdr[ql * 8 + dd]) * rinv[ql];
          cc += 1.f;
        }
        cp += p;
        apS[ql * 140 + ksub * 16 + l15] = p;
      }
      cp += __shfl_xor(cp, 16);
      cp += __shfl_xor(cp, 32);
      if (quad == 0) atomicAdd(&colacc[ksub * 16 + l15], cp);
      if (h0) {
        cc += __shfl_xor(cc, 16);
        cc += __shfl_xor(cc, 32);
        if (quad == 0) atomicAdd(&colcnt[ksub * 16 + l15], cc);
      }
    }
    __syncthreads();

    // coalesced attn write from apS + flush column accumulators
    {
      int r = t >> 3, l8 = t & 7;
      int qg = q0 + r;
      if (qg < E_) {
        size_t rowoff = ((size_t)(b * HH + h) * E_ + qg) * E_ + k0;
        int kmax = E_ - k0;  // 128 or 92
#pragma unroll
        for (int i = 0; i < 4; i++) {
          int kk = (l8 + 8 * i) * 4;
          if (kk < kmax)
            *(float4*)(attn + rowoff + kk) = *(float4*)(apS + r * 140 + kk);
        }
      }
    }
    if (t < 128) {
      int kcol = k0 + t;
      if (kcol < E_) {
        atomicAdd(asum + b * E_ + kcol, colacc[t]);
        if (h0) atomicAdd(validf + b * E_ + kcol, colcnt[t]);
      }
      colacc[t] = 0.f;
      colcnt[t] = 0.f;
    }
  }
}

// ------------------------------------------- FC + residual + transpose out
__global__ __launch_bounds__(256) void k3_fc(const float* __restrict__ ao,
                                             const float* __restrict__ Wfc,
                                             const float* __restrict__ xt,
                                             float* __restrict__ xout) {
  __shared__ __align__(16) float smem[9472];
  float* AT = smem;
  float* Bt = smem + 1152;
  float* ot = smem;
  const int m0 = blockIdx.x * 32;
  const int t = threadIdx.x;
  const int rg = t >> 5, cg = t & 31;
  float acc[4][8];
#pragma unroll
  for (int i = 0; i < 4; i++)
#pragma unroll
    for (int c = 0; c < 8; c++) acc[i][c] = 0.f;

  for (int k0 = 0; k0 < 256; k0 += 32) {
    __syncthreads();
    {
      int r = t >> 3, cq = t & 7;
      int m = m0 + r;
      if (m > MM - 1) m = MM - 1;
      float4 f = *(const float4*)(ao + (size_t)m * 256 + k0 + cq * 4);
      AT[(cq * 4 + 0) * 36 + r] = f.x;
      AT[(cq * 4 + 1) * 36 + r] = f.y;
      AT[(cq * 4 + 2) * 36 + r] = f.z;
      AT[(cq * 4 + 3) * 36 + r] = f.w;
    }
#pragma unroll
    for (int ii = 0; ii < 8; ii++) {
      int id = t + 256 * ii;
      int kk = id >> 6, nq = id & 63;
      *(float4*)(Bt + kk * 260 + nq * 4) =
          *(const float4*)(Wfc + (size_t)(k0 + kk) * 256 + nq * 4);
    }
    __syncthreads();
#pragma unroll
    for (int kk = 0; kk < 32; kk++) {
      float4 a4 = *(float4*)(AT + kk * 36 + rg * 4);
      float4 b0 = *(float4*)(Bt + kk * 260 + cg * 8);
      float4 b1 = *(float4*)(Bt + kk * 260 + cg * 8 + 4);
      float aa[4] = {a4.x, a4.y, a4.z, a4.w};
      float bb[8] = {b0.x, b0.y, b0.z, b0.w, b1.x, b1.y, b1.z, b1.w};
#pragma unroll
      for (int i = 0; i < 4; i++)
#pragma unroll
        for (int c = 0; c < 8; c++) acc[i][c] = fmaf(aa[i], bb[c], acc[i][c]);
    }
  }
  __syncthreads();
#pragma unroll
  for (int i = 0; i < 4; i++) {
    int m = m0 + rg * 4 + i;
    int mc = (m < MM) ? m : (MM - 1);
    float4 r0 = *(const float4*)(xt + (size_t)mc * 256 + cg * 8);
    float4 r1 = *(const float4*)(xt + (size_t)mc * 256 + cg * 8 + 4);
    float rr[8] = {r0.x, r0.y, r0.z, r0.w, r1.x, r1.y, r1.z, r1.w};
#pragma unroll
    for (int c = 0; c < 8; c++)
      ot[(cg * 8 + c) * 37 + rg * 4 + i] = acc[i][c] + rr[c];
  }
  __syncthreads();
  {
    int l = t & 31, dg = t >> 5;
    int m = m0 + l;
    if (m < MM) {
      int b = m / E_, e = m % E_;
      float* obase = xout + (size_t)b * D_ * E_ + e;
#pragma unroll
      for (int ii = 0; ii < 32; ii++) {
        int d = dg + ii * 8;
        obase[(size_t)d * E_] = ot[d * 37 + l];
      }
    }
  }
}

__global__ __launch_bounds__(256) void k5_div(const float* __restrict__ asum,
                                              const float* __restrict__ validf,
                                              float* __restrict__ ape) {
  int i = blockIdx.x * 256 + threadIdx.x;
  if (i < BB * E_) ape[i] = asum[i] / validf[i];
}

// ---------------------------------------------------------------- launcher
extern "C" void kernel_launch(void* const* d_in, const int* in_sizes, int n_in,
                              void* d_out, int out_size, void* d_ws,
                              size_t ws_size, hipStream_t stream) {
  const float* x = (const float*)d_in[0];
  const int* dist = (const int*)d_in[1];
  const float* Wq = (const float*)d_in[2];
  const float* Wk = (const float*)d_in[3];
  const float* Wv = (const float*)d_in[4];
  const float* Wfc = (const float*)d_in[5];
  const float* lnw = (const float*)d_in[6];
  const float* lnb = (const float*)d_in[7];
  const float* rpr = (const float*)d_in[8];

  float* out0 = (float*)d_out;
  float* attn = out0 + 1536000;
  float* ape = out0 + 73536000;

  float* ws = (float*)d_ws;
  float* xt = ws;                                  // [6000,256] f32
  float* qn = ws + 1536000;                        // [6000,256] f32
  unsigned short* qb16 = (unsigned short*)(ws + 3072000);  // [6000,256] bf16
  unsigned short* kb16 = (unsigned short*)(ws + 3840000);
  unsigned short* vb16 = (unsigned short*)(ws + 4608000);
  float* ao = ws + 5376000;                        // [6000,256] f32
  float* asum = ws + 6912000;                      // [6000]
  float* validf = ws + 6918000;                    // [6000]

  hipMemsetAsync(asum, 0, 12000 * sizeof(float), stream);  // asum + validf

  t0_transpose<<<dim3(8, 47, 4), dim3(32, 8), 0, stream>>>(x, xt);
  k1_ln<<<MM, 256, 0, stream>>>(xt, lnw, lnb, qn);
  k_gemm_proj<<<dim3(188, 3), 256, 0, stream>>>(xt, qn, Wq, Wk, Wv, qb16, kb16,
                                                vb16);
  k2_attn<<<1536, 256, 0, stream>>>(qb16, kb16, vb16, dist, rpr, attn, ao,
                                    asum, validf);
  k3_fc<<<188, 256, 0, stream>>>(ao, Wfc, xt, out0);
  k5_div<<<24, 256, 0, stream>>>(asum, validf, ape);
}

// Round 4
// 767.192 us; speedup vs baseline: 2.0247x; 1.0399x over previous
//
#include <hip/hip_runtime.h>

// MeshAttention gfx950 — round 4: proven round-2 attention kernel (unchanged
// except ao stored as bf16) + MFMA bf16 GEMMs for projections and FC.
// B=4, H=8, E=1500, D=256, DK=DV=32, P+1=6, mask = dist<=3.

#define E_ 1500
#define D_ 256
#define HH 8
#define BB 4
#define MM (BB * E_)  // 6000
#define NKT 12

typedef float f32x4 __attribute__((ext_vector_type(4)));
typedef short short8 __attribute__((ext_vector_type(8)));

static __device__ inline unsigned short f2bf(float f) {
  unsigned u = __float_as_uint(f);
  unsigned r = (u + 0x7fff + ((u >> 16) & 1)) >> 16;
  return (unsigned short)r;
}
static __device__ inline float bf2f(unsigned short u) {
  return __uint_as_float(((unsigned)u) << 16);
}

// ------------------------------------------- transpose: x -> xt f32, xtb bf16
__global__ __launch_bounds__(256) void t0_transpose(const float* __restrict__ x,
                                                    float* __restrict__ xt,
                                                    unsigned short* __restrict__ xtb) {
  __shared__ float tl[32][33];
  const int b = blockIdx.z;
  const int dt = blockIdx.x * 32;
  const int et = blockIdx.y * 32;
  const int tx = threadIdx.x, ty = threadIdx.y;
#pragma unroll
  for (int j = 0; j < 4; j++) {
    int d = dt + ty + j * 8;
    int e = et + tx;
    float v = 0.f;
    if (e < E_) v = x[(size_t)b * D_ * E_ + (size_t)d * E_ + e];
    tl[ty + j * 8][tx] = v;
  }
  __syncthreads();
#pragma unroll
  for (int j = 0; j < 4; j++) {
    int e = et + ty + j * 8;
    int d = dt + tx;
    if (e < E_) {
      float v = tl[tx][ty + j * 8];
      size_t idx = ((size_t)b * E_ + e) * D_ + d;
      xt[idx] = v;
      xtb[idx] = f2bf(v);
    }
  }
}

// ------------------------------------------- weight convert+transpose -> bf16
// W[mat] is [256 k][256 n] f32 row-major; WT[mat] is [256 n][256 k] bf16.
__global__ __launch_bounds__(256) void t1_wt(const float* __restrict__ Wq,
                                             const float* __restrict__ Wk,
                                             const float* __restrict__ Wv,
                                             const float* __restrict__ Wfc,
                                             unsigned short* __restrict__ WT) {
  __shared__ float tl[32][33];
  const int mat = blockIdx.z;
  const float* W = (mat == 0) ? Wq : (mat == 1) ? Wk : (mat == 2) ? Wv : Wfc;
  const int kt = blockIdx.x * 32, nt = blockIdx.y * 32;
  const int tx = threadIdx.x, ty = threadIdx.y;
#pragma unroll
  for (int j = 0; j < 4; j++)
    tl[ty + j * 8][tx] = W[(size_t)(kt + ty + j * 8) * 256 + nt + tx];
  __syncthreads();
#pragma unroll
  for (int j = 0; j < 4; j++)
    WT[(size_t)mat * 65536 + (size_t)(nt + ty + j * 8) * 256 + kt + tx] =
        f2bf(tl[tx][ty + j * 8]);
}

// ---------------------------------------------------------------- layernorm
__global__ __launch_bounds__(256) void k1_ln(const float* __restrict__ xt,
                                             const float* __restrict__ lnw,
                                             const float* __restrict__ lnb,
                                             unsigned short* __restrict__ qnb) {
  const int m = blockIdx.x;
  const int t = threadIdx.x;
  float v = xt[(size_t)m * D_ + t];
  float s = v, s2 = v * v;
#pragma unroll
  for (int o = 1; o < 64; o <<= 1) {
    s += __shfl_xor(s, o);
    s2 += __shfl_xor(s2, o);
  }
  __shared__ float ps[4], ps2[4], mv[2];
  const int w = t >> 6;
  if ((t & 63) == 0) { ps[w] = s; ps2[w] = s2; }
  __syncthreads();
  if (t == 0) {
    float ts = ps[0] + ps[1] + ps[2] + ps[3];
    float ts2 = ps2[0] + ps2[1] + ps2[2] + ps2[3];
    float mu = ts * (1.f / 256.f);
    float var = ts2 * (1.f / 256.f) - mu * mu;
    mv[0] = mu;
    mv[1] = rsqrtf(var + 1e-6f);
  }
  __syncthreads();
  qnb[(size_t)m * D_ + t] = f2bf((v - mv[0]) * mv[1] * lnw[t] + lnb[t]);
}

// ------------------------------------------------- projections, LDS-free mfma
// grid (94, 12): mat = y>>2 (0=q,1=k,2=v), 64-col group = (y&3)*64.
// All outputs row-major [6000,256] bf16; q pre-scaled by 1/sqrt(32).
__global__ __launch_bounds__(256) void kproj(
    const unsigned short* __restrict__ xtb, const unsigned short* __restrict__ qnb,
    const unsigned short* __restrict__ WT, unsigned short* __restrict__ qb,
    unsigned short* __restrict__ kb, unsigned short* __restrict__ vb) {
  const int mat = blockIdx.y >> 2;
  const int n0 = (blockIdx.y & 3) * 64;
  const int m0 = blockIdx.x * 64;
  const int t = threadIdx.x;
  const int w = t >> 6, l = t & 63, quad = l >> 4, l15 = l & 15;
  const unsigned short* A = (mat == 0) ? qnb : xtb;
  const unsigned short* B = WT + (size_t)mat * 65536;
  unsigned short* dst = (mat == 0) ? qb : ((mat == 1) ? kb : vb);
  const float scale = (mat == 0) ? 0.17677669529663687f : 1.0f;

  int mrow = m0 + w * 16 + l15;
  if (mrow > MM - 1) mrow = MM - 1;
  short8 af[8];
#pragma unroll
  for (int kc = 0; kc < 8; kc++)
    af[kc] = *(const short8*)(A + (size_t)mrow * 256 + kc * 32 + quad * 8);

#pragma unroll
  for (int ntile = 0; ntile < 4; ntile++) {
    const int n = n0 + ntile * 16 + l15;
    f32x4 acc = {0.f, 0.f, 0.f, 0.f};
#pragma unroll
    for (int kc = 0; kc < 8; kc++) {
      short8 bf = *(const short8*)(B + (size_t)n * 256 + kc * 32 + quad * 8);
      acc = __builtin_amdgcn_mfma_f32_16x16x32_bf16(af[kc], bf, acc, 0, 0, 0);
    }
#pragma unroll
    for (int r = 0; r < 4; r++) {
      int m = m0 + w * 16 + quad * 4 + r;
      if (m < MM) dst[(size_t)m * 256 + n] = f2bf(acc[r] * scale);
    }
  }
}

// ---------------------------------------------------------------- attention
// (round-2 proven kernel; only change: ao stored as bf16)
__global__ __launch_bounds__(256) void k2_attn(
    const unsigned short* __restrict__ qb, const unsigned short* __restrict__ kb,
    const unsigned short* __restrict__ vb, const int* __restrict__ dist,
    const float* __restrict__ rpr, float* __restrict__ attn,
    unsigned short* __restrict__ aob, float* __restrict__ asum,
    float* __restrict__ validf) {
  __shared__ __align__(16) unsigned short qS[32 * 40];
  __shared__ __align__(16) unsigned short kS[128 * 40];
  __shared__ __align__(16) float unionBuf[32 * 140];  // apS | pS+vT
  __shared__ float qdr[32 * 8];
  __shared__ float rowl[32], rinv[32];
  __shared__ float colacc[128], colcnt[128];

  unsigned short* pS = (unsigned short*)unionBuf;  // [32 q][136]
  unsigned short* vT = pS + 32 * 136;              // [32 dv][136]
  float* apS = unionBuf;                           // [32 q][140]

  const int n = blockIdx.x;
  const int h = (n >> 3) & 7;
  const int slice = (n & 7) + ((n >> 6) << 3);
  if (slice >= 188) return;
  const int b = slice / 47;
  const int qt = slice % 47;
  const int q0 = qt * 32;
  const int t = threadIdx.x;
  const int w = t >> 6, l = t & 63, quad = l >> 4, l15 = l & 15;
  const int qsub = w & 1, khalf = w >> 1;
  const bool h0 = (h == 0);

  {
    int r = t >> 3, c8 = t & 7;
    int qg = q0 + r;
    unsigned long long v = 0ull;
    if (qg < E_)
      v = *(const unsigned long long*)(qb + ((size_t)(b * E_ + qg)) * 256 +
                                       h * 32 + c8 * 4);
    *(unsigned long long*)(qS + r * 40 + c8 * 4) = v;
  }
  if (t < 32) rowl[t] = 0.f;
  if (t < 128) { colacc[t] = 0.f; colcnt[t] = 0.f; }
  __syncthreads();

  if (t < 192) {
    int q = t / 6, p = t - (t / 6) * 6;
    float s = 0.f;
#pragma unroll
    for (int d = 0; d < 32; d++) s += bf2f(qS[q * 40 + d]) * rpr[p * 32 + d];
    qdr[q * 8 + p] = s;
  }
  __syncthreads();

  short8 aq = *(short8*)(qS + (qsub * 16 + l15) * 40 + quad * 8);
  f32x4 accPV = {0.f, 0.f, 0.f, 0.f};

  // ================= sweep 1: rowsum + unnormalized PV =================
  for (int kt = 0; kt < NKT; kt++) {
    const int k0 = kt * 128;
    __syncthreads();
    {
      int r = t >> 1, half = t & 1;
      int kg = k0 + r;
      unsigned short* dk = kS + r * 40 + half * 16;
      if (kg < E_) {
        const unsigned short* kp =
            kb + ((size_t)(b * E_ + kg)) * 256 + h * 32 + half * 16;
        const unsigned short* vp =
            vb + ((size_t)(b * E_ + kg)) * 256 + h * 32 + half * 16;
        uint4 a0 = *(const uint4*)kp;
        uint4 a1 = *(const uint4*)(kp + 8);
        *(uint4*)dk = a0;
        *(uint4*)(dk + 8) = a1;
        uint4 b0 = *(const uint4*)vp;
        uint4 b1 = *(const uint4*)(vp + 8);
        unsigned short vv[16];
        *(uint4*)vv = b0;
        *(uint4*)(vv + 8) = b1;
#pragma unroll
        for (int j = 0; j < 16; j++) vT[(half * 16 + j) * 136 + r] = vv[j];
      } else {
        uint4 z = {0u, 0u, 0u, 0u};
        *(uint4*)dk = z;
        *(uint4*)(dk + 8) = z;
#pragma unroll
        for (int j = 0; j < 16; j++) vT[(half * 16 + j) * 136 + r] = 0;
      }
    }
    __syncthreads();

    f32x4 c[4];
#pragma unroll
    for (int j = 0; j < 4; j++) {
      int ksub = khalf * 4 + j;
      short8 bk = *(short8*)(kS + (ksub * 16 + l15) * 40 + quad * 8);
      f32x4 z = {0.f, 0.f, 0.f, 0.f};
      c[j] = __builtin_amdgcn_mfma_f32_16x16x32_bf16(aq, bk, z, 0, 0, 0);
    }

    float rs[4] = {0.f, 0.f, 0.f, 0.f};
#pragma unroll
    for (int j = 0; j < 4; j++) {
      int ksub = khalf * 4 + j;
      int kcol = k0 + ksub * 16 + l15;
      bool kok = kcol < E_;
#pragma unroll
      for (int r = 0; r < 4; r++) {
        int ql = qsub * 16 + quad * 4 + r;
        int qg = q0 + ql;
        int dd = 8;
        if (kok && qg < E_) dd = dist[((size_t)b * E_ + qg) * E_ + kcol];
        float e = 0.f;
        if (dd <= 3) e = __expf(c[j][r] + qdr[ql * 8 + dd]);
        rs[r] += e;
        pS[ql * 136 + ksub * 16 + l15] = f2bf(e);
      }
    }
#pragma unroll
    for (int r = 0; r < 4; r++) {
      float v = rs[r];
      v += __shfl_xor(v, 1);
      v += __shfl_xor(v, 2);
      v += __shfl_xor(v, 4);
      v += __shfl_xor(v, 8);
      if (l15 == 0) atomicAdd(&rowl[qsub * 16 + quad * 4 + r], v);
    }
    __syncthreads();

#pragma unroll
    for (int ch = 0; ch < 4; ch++) {
      short8 ap = *(short8*)(pS + (qsub * 16 + l15) * 136 + ch * 32 + quad * 8);
      short8 bv =
          *(short8*)(vT + (khalf * 16 + l15) * 136 + ch * 32 + quad * 8);
      accPV = __builtin_amdgcn_mfma_f32_16x16x32_bf16(ap, bv, accPV, 0, 0, 0);
    }
  }
  __syncthreads();
  if (t < 32) {
    float lsum = rowl[t];
    rinv[t] = (lsum > 0.f) ? 1.f / lsum : 0.f;
  }
  __syncthreads();

  // write ao = PV / l  (bf16)
#pragma unroll
  for (int r = 0; r < 4; r++) {
    int ql = qsub * 16 + quad * 4 + r;
    int qg = q0 + ql;
    if (qg < E_)
      aob[((size_t)(b * E_ + qg)) * 256 + h * 32 + khalf * 16 + l15] =
          f2bf(accPV[r] * rinv[ql]);
  }

  // ================= sweep 2: normalized attn + column sums =================
  for (int kt = 0; kt < NKT; kt++) {
    const int k0 = kt * 128;
    __syncthreads();
    {
      int r = t >> 1, half = t & 1;
      int kg = k0 + r;
      unsigned short* dk = kS + r * 40 + half * 16;
      if (kg < E_) {
        const unsigned short* kp =
            kb + ((size_t)(b * E_ + kg)) * 256 + h * 32 + half * 16;
        uint4 a0 = *(const uint4*)kp;
        uint4 a1 = *(const uint4*)(kp + 8);
        *(uint4*)dk = a0;
        *(uint4*)(dk + 8) = a1;
      } else {
        uint4 z = {0u, 0u, 0u, 0u};
        *(uint4*)dk = z;
        *(uint4*)(dk + 8) = z;
      }
    }
    __syncthreads();

    f32x4 c[4];
#pragma unroll
    for (int j = 0; j < 4; j++) {
      int ksub = khalf * 4 + j;
      short8 bk = *(short8*)(kS + (ksub * 16 + l15) * 40 + quad * 8);
      f32x4 z = {0.f, 0.f, 0.f, 0.f};
      c[j] = __builtin_amdgcn_mfma_f32_16x16x32_bf16(aq, bk, z, 0, 0, 0);
    }

#pragma unroll
    for (int j = 0; j < 4; j++) {
      int ksub = khalf * 4 + j;
      int kcol = k0 + ksub * 16 + l15;
      bool kok = kcol < E_;
      float cp = 0.f, cc = 0.f;
#pragma unroll
      for (int r = 0; r < 4; r++) {
        int ql = qsub * 16 + quad * 4 + r;
        int qg = q0 + ql;
        int dd = 8;
        if (kok && qg < E_) dd = dist[((size_t)b * E_ + qg) * E_ + kcol];
        float p = 0.f;
        if (dd <= 3) {
          p = __expf(c[j][r] + qdr[ql * 8 + dd]) * rinv[ql];
          cc += 1.f;
        }
        cp += p;
        apS[ql * 140 + ksub * 16 + l15] = p;
      }
      cp += __shfl_xor(cp, 16);
      cp += __shfl_xor(cp, 32);
      if (quad == 0) atomicAdd(&colacc[ksub * 16 + l15], cp);
      if (h0) {
        cc += __shfl_xor(cc, 16);
        cc += __shfl_xor(cc, 32);
        if (quad == 0) atomicAdd(&colcnt[ksub * 16 + l15], cc);
      }
    }
    __syncthreads();

    {
      int r = t >> 3, l8 = t & 7;
      int qg = q0 + r;
      if (qg < E_) {
        size_t rowoff = ((size_t)(b * HH + h) * E_ + qg) * E_ + k0;
        int kmax = E_ - k0;
#pragma unroll
        for (int i = 0; i < 4; i++) {
          int kk = (l8 + 8 * i) * 4;
          if (kk < kmax)
            *(float4*)(attn + rowoff + kk) = *(float4*)(apS + r * 140 + kk);
        }
      }
    }
    if (t < 128) {
      int kcol = k0 + t;
      if (kcol < E_) {
        atomicAdd(asum + b * E_ + kcol, colacc[t]);
        if (h0) atomicAdd(validf + b * E_ + kcol, colcnt[t]);
      }
      colacc[t] = 0.f;
      colcnt[t] = 0.f;
    }
  }
}

// ------------------------------------------- FC + residual, LDS-free mfma
// grid (94, 4). C rows = consecutive e -> float4 stores along E (free transpose).
__global__ __launch_bounds__(256) void k_fc(const unsigned short* __restrict__ aob,
                                            const unsigned short* __restrict__ WT,
                                            const float* __restrict__ x,
                                            float* __restrict__ xout) {
  const int n0 = blockIdx.y * 64;
  const int m0 = blockIdx.x * 64;
  const int t = threadIdx.x;
  const int w = t >> 6, l = t & 63, quad = l >> 4, l15 = l & 15;
  const unsigned short* B = WT + (size_t)3 * 65536;

  int mrow = m0 + w * 16 + l15;
  if (mrow > MM - 1) mrow = MM - 1;
  short8 af[8];
#pragma unroll
  for (int kc = 0; kc < 8; kc++)
    af[kc] = *(const short8*)(aob + (size_t)mrow * 256 + kc * 32 + quad * 8);

#pragma unroll
  for (int ntile = 0; ntile < 4; ntile++) {
    const int nc = n0 + ntile * 16 + l15;  // output d column
    f32x4 acc = {0.f, 0.f, 0.f, 0.f};
#pragma unroll
    for (int kc = 0; kc < 8; kc++) {
      short8 bf = *(const short8*)(B + (size_t)nc * 256 + kc * 32 + quad * 8);
      acc = __builtin_amdgcn_mfma_f32_16x16x32_bf16(af[kc], bf, acc, 0, 0, 0);
    }
    int m = m0 + w * 16 + quad * 4;  // 4 consecutive rows (same b: E_%4==0)
    if (m < MM) {
      int bb = m / E_, e = m - bb * E_;
      size_t idx = ((size_t)bb * 256 + nc) * E_ + e;
      float4 rx = *(const float4*)(x + idx);
      *(float4*)(xout + idx) = make_float4(acc[0] + rx.x, acc[1] + rx.y,
                                           acc[2] + rx.z, acc[3] + rx.w);
    }
  }
}

__global__ __launch_bounds__(256) void k5_div(const float* __restrict__ asum,
                                              const float* __restrict__ validf,
                                              float* __restrict__ ape) {
  int i = blockIdx.x * 256 + threadIdx.x;
  if (i < BB * E_) ape[i] = asum[i] / validf[i];
}

// ---------------------------------------------------------------- launcher
extern "C" void kernel_launch(void* const* d_in, const int* in_sizes, int n_in,
                              void* d_out, int out_size, void* d_ws,
                              size_t ws_size, hipStream_t stream) {
  const float* x = (const float*)d_in[0];
  const int* dist = (const int*)d_in[1];
  const float* Wq = (const float*)d_in[2];
  const float* Wk = (const float*)d_in[3];
  const float* Wv = (const float*)d_in[4];
  const float* Wfc = (const float*)d_in[5];
  const float* lnw = (const float*)d_in[6];
  const float* lnb = (const float*)d_in[7];
  const float* rpr = (const float*)d_in[8];

  float* out0 = (float*)d_out;
  float* attn = out0 + 1536000;
  float* ape = out0 + 73536000;

  float* ws = (float*)d_ws;
  float* xt = ws;                                            // [6000,256] f32
  unsigned short* xtb = (unsigned short*)(ws + 1536000);     // bf16
  unsigned short* qnb = (unsigned short*)(ws + 2304000);     // bf16
  unsigned short* qb = (unsigned short*)(ws + 3072000);      // bf16
  unsigned short* kb = (unsigned short*)(ws + 3840000);      // bf16
  unsigned short* vb = (unsigned short*)(ws + 4608000);      // bf16
  unsigned short* aob = (unsigned short*)(ws + 5376000);     // bf16
  unsigned short* WT = (unsigned short*)(ws + 6144000);      // [4,256,256] bf16
  float* asum = ws + 6275072;                                // [6000]
  float* validf = ws + 6281072;                              // [6000]

  hipMemsetAsync(asum, 0, 12000 * sizeof(float), stream);

  t0_transpose<<<dim3(8, 47, 4), dim3(32, 8), 0, stream>>>(x, xt, xtb);
  t1_wt<<<dim3(8, 8, 4), dim3(32, 8), 0, stream>>>(Wq, Wk, Wv, Wfc, WT);
  k1_ln<<<MM, 256, 0, stream>>>(xt, lnw, lnb, qnb);
  kproj<<<dim3(94, 12), 256, 0, stream>>>(xtb, qnb, WT, qb, kb, vb);
  k2_attn<<<1536, 256, 0, stream>>>(qb, kb, vb, dist, rpr, attn, aob, asum,
                                    validf);
  k_fc<<<dim3(94, 4), 256, 0, stream>>>(aob, WT, x, out0);
  k5_div<<<24, 256, 0, stream>>>(asum, validf, ape);
}